// Round 18
// baseline (103.931 us; speedup 1.0000x reference)
//
#include <hip/hip_runtime.h>

#define BB 8
#define CC 64
#define HH 128
#define WW 128
#define HWSZ (HH*WW)

typedef _Float16 h16;
typedef __attribute__((ext_vector_type(8))) _Float16 h16x8;
typedef __attribute__((ext_vector_type(4))) _Float16 h16x4;
typedef __attribute__((ext_vector_type(2))) _Float16 h16x2;
typedef __attribute__((ext_vector_type(4))) float f32x4;

typedef const __attribute__((address_space(1))) unsigned int* gptr_t;
typedef __attribute__((address_space(3))) unsigned int* lptr_t;

// ---- pack helper ----
__device__ __forceinline__ void conv_pack(int j, int NCG, const float* w,
                                          int maxo, h16* dst) {
  int e = j & 7, l4 = (j >> 3) & 3, l15 = (j >> 5) & 15, f = (j >> 9) & 1;
  int cg = (j >> 10) & (NCG - 1), kt = (j >> 10) / NCG;
  int o = f * 16 + l15, c = cg * 32 + l4 * 8 + e;
  int CINw = NCG * 32;
  dst[j] = (o < maxo) ? (h16)w[(o * CINw + c) * 9 + kt] : (h16)0.f;
}

// ---------------- fused prep: g-MLP + weight pack + x transpose ----------------
__global__ __launch_bounds__(256) void prep_kernel(
    const float* __restrict__ bsize, const float* __restrict__ gw1,
    const float* __restrict__ gb1, const float* __restrict__ gw2,
    const float* __restrict__ gb2, float* __restrict__ g,
    const float* __restrict__ lw1, const float* __restrict__ lw2,
    const float* __restrict__ fw1, const float* __restrict__ fw2,
    const float* __restrict__ dw, h16* __restrict__ cwq,
    h16* __restrict__ dwq, h16* __restrict__ fw2w,
    const float* __restrict__ x, h16* __restrict__ xt) {
  __shared__ float hbuf[BB][64];
  const int blk = blockIdx.x;
  const int tid = threadIdx.x;
  if (blk == 0) {
#pragma unroll
    for (int i2 = 0; i2 < 2; ++i2) {
      int idx = i2 * 256 + tid;
      int b = idx >> 6, i = idx & 63;
      float v = fmaf(bsize[b * 2 + 0], gw1[i * 2 + 0],
                     fmaf(bsize[b * 2 + 1], gw1[i * 2 + 1], gb1[i]));
      hbuf[b][i] = fmaxf(v, 0.f);
    }
    __syncthreads();
    int b = tid >> 5, j = tid & 31;
    float acc = gb2[j];
#pragma unroll
    for (int i = 0; i < 64; ++i) acc = fmaf(hbuf[b][i], gw2[j * 64 + i], acc);
    g[b * 32 + j] = acc;
  } else if (blk <= 360) {
    int i = (blk - 1) * 256 + tid;
    if (i < 18432) {
      conv_pack(i, 2, lw1, 32, cwq);
    } else if (i < 27648) {
      conv_pack(i - 18432, 1, lw2, 32, cwq + 18432);
    } else if (i < 46080) {
      conv_pack(i - 27648, 2, fw1, 32, cwq + 27648);
    } else if (i < 55296) {
      conv_pack(i - 46080, 1, fw2, 18, cwq + 46080);
      conv_pack(i - 46080, 1, fw2, 18, fw2w);
    } else if (i < 55296 + 36864) {
      int j = i - 55296;
      int e = j & 7, l4 = (j >> 3) & 3, l15 = (j >> 5) & 15;
      int og = (j >> 9) & 3, cg = (j >> 11) & 1, kt = j >> 12;
      int o = og * 16 + l15, c = cg * 32 + l4 * 8 + e;
      dwq[j] = (h16)dw[(o * 64 + c) * 9 + kt];
    }
  } else {
    int j = blk - 361;
    int b = (1 + j) & 7;
    int slot = j >> 3;
    int t = b * 16384 + slot * 256 + tid;
    int p = t & 16383;
    const float* xb = x + (size_t)b * 64 * HWSZ + p;
    h16* ob = xt + (size_t)t * 64;
#pragma unroll
    for (int c0 = 0; c0 < 64; c0 += 8) {
      h16x8 v;
#pragma unroll
      for (int i = 0; i < 8; ++i) v[i] = (h16)xb[(size_t)(c0 + i) * HWSZ];
      *(h16x8*)(ob + c0) = v;
    }
  }
}

// ---------------- conv 3x3 via MFMA + 4-row LDS tile, 2 output rows (R12) ----------------
template <int NCG, bool GFUSE, bool RELU, int OMODE>
__global__ __launch_bounds__(512) void conv_mfma_kernel(
    const h16* __restrict__ in, const h16* __restrict__ cwq,
    const float* __restrict__ bias, const float* __restrict__ g,
    h16* __restrict__ outv) {
  constexpr int CINS = GFUSE ? 32 : NCG * 32;
  constexpr int NS = CINS / 8;
  constexpr int LOG2NS = (NS == 8) ? 3 : 2;
  constexpr int NCHUNK = 4 * 128 * NS;
  __shared__ __align__(16) h16 sh[4 * 128 * CINS];
  const int wgid = (blockIdx.x & 7) * 64 + (blockIdx.x >> 3);
  const int b = wgid >> 6;
  const int h0 = (wgid & 63) * 2;
  const int lane = threadIdx.x & 63, wave = threadIdx.x >> 6;
  const int wr = wave >> 2, wv = wave & 3;
  const int h = h0 + wr;
  const int l15 = lane & 15, l4 = lane >> 4;
  const h16* inb = in + (size_t)b * HWSZ * CINS;

#pragma unroll
  for (int it = 0; it < NCHUNK / 512; ++it) {
    int q = it * 512 + threadIdx.x;
    int sp = q & (NS - 1), pr = q >> LOG2NS;
    int r = pr >> 7, px = pr & 127;
    int gy = min(max(h0 - 1 + r, 0), HH - 1);
    int s = sp ^ (px & (NS - 1));
    const h16* src = inb + ((size_t)gy * WW + px) * CINS + s * 8;
    __builtin_amdgcn_global_load_lds(
        (gptr_t)src, (lptr_t)(sh + (size_t)(it * 512 + wave * 64) * 8), 16, 0, 0);
  }

  const h16x8 zfr = {0, 0, 0, 0, 0, 0, 0, 0};
  h16x8 gfr = zfr;
  if (GFUSE) {
#pragma unroll
    for (int i = 0; i < 8; ++i) gfr[i] = (h16)g[b * 32 + l4 * 8 + i];
  }
  __syncthreads();

  f32x4 acc[2][2];
#pragma unroll
  for (int f = 0; f < 2; ++f)
#pragma unroll
    for (int j = 0; j < 2; ++j) acc[f][j] = (f32x4){0.f, 0.f, 0.f, 0.f};

#pragma unroll
  for (int kt = 0; kt < 9; ++kt) {
    const int ki = kt / 3 - 1, kj = kt % 3 - 1;
    const int y = h + ki;
    const bool yok = (unsigned)y < HH;
    const int r = ki + 1 + wr;
    int xs[2];
    bool ok[2];
#pragma unroll
    for (int j = 0; j < 2; ++j) {
      int xx = wv * 32 + j * 16 + l15 + kj;
      ok[j] = yok && ((unsigned)xx < WW);
      xs[j] = min(max(xx, 0), WW - 1);
    }
#pragma unroll
    for (int cg = 0; cg < NCG; ++cg) {
      const h16* aq = cwq + (size_t)((kt * NCG + cg) * 2) * 512 + l15 * 32 + l4 * 8;
      h16x8 afr0 = *(const h16x8*)(aq);
      h16x8 afr1 = *(const h16x8*)(aq + 512);
#pragma unroll
      for (int j = 0; j < 2; ++j) {
        h16x8 bv;
        if (GFUSE && cg == 0) {
          bv = ok[j] ? gfr : zfr;
        } else {
          const int s = (!GFUSE && NCG == 2) ? cg * 4 + l4 : l4;
          h16x8 ld = *(const h16x8*)(sh + (r * 128 + xs[j]) * CINS +
                                     ((s ^ (xs[j] & (NS - 1))) * 8));
          bv = ok[j] ? ld : zfr;
        }
        acc[0][j] = __builtin_amdgcn_mfma_f32_16x16x32_f16(afr0, bv, acc[0][j], 0, 0, 0);
        acc[1][j] = __builtin_amdgcn_mfma_f32_16x16x32_f16(afr1, bv, acc[1][j], 0, 0, 0);
      }
    }
  }
  if (OMODE == 0) {
    h16* ob = outv + (size_t)b * HWSZ * 32;
#pragma unroll
    for (int f = 0; f < 2; ++f)
#pragma unroll
      for (int j = 0; j < 2; ++j) {
        int p = h * WW + wv * 32 + j * 16 + l15;
        int o0 = f * 16 + l4 * 4;
        h16x4 st;
#pragma unroll
        for (int r2 = 0; r2 < 4; ++r2) {
          float v = acc[f][j][r2] + bias[o0 + r2];
          if (RELU) v = fmaxf(v, 0.f);
          st[r2] = (h16)v;
        }
        *(h16x4*)(ob + (size_t)p * 32 + o0) = st;
      }
  } else {
    h16* ob = outv + (size_t)b * HWSZ * 24;
#pragma unroll
    for (int j = 0; j < 2; ++j) {
      int p = h * WW + wv * 32 + j * 16 + l15;
      {
        int o0 = l4 * 4;
        h16x4 st;
#pragma unroll
        for (int r2 = 0; r2 < 4; ++r2) st[r2] = (h16)(acc[0][j][r2] + bias[o0 + r2]);
        *(h16x4*)(ob + (size_t)p * 24 + o0) = st;
      }
      if (l4 == 0) {
        h16x2 st2;
        st2[0] = (h16)(acc[1][j][0] + bias[16]);
        st2[1] = (h16)(acc[1][j][1] + bias[17]);
        *(h16x2*)(ob + (size_t)p * 24 + 16) = st2;
      }
    }
  }
}

// ---------------- deformable conv: R12 geometry; FUSED computes offsets in-kernel ----------------
// FUSED: aux = t2 (channel-last 32, in ws). else: aux = offc (stride 24).
template <bool FUSED>
__global__ __launch_bounds__(256) void deform_mfma_kernel(
    const h16* __restrict__ xt, const h16* __restrict__ aux,
    const h16* __restrict__ dwq, const float* __restrict__ db,
    const h16* __restrict__ fw2q, const float* __restrict__ fb2,
    float* __restrict__ out) {
  __shared__ __align__(16) h16 sh[5 * 72 * 64];
  __shared__ __align__(16) h16 sh2[FUSED ? 3 * 72 * 32 : 8];
  const int wgid = (blockIdx.x & 7) * 256 + (blockIdx.x >> 3);
  const int b = wgid >> 8;
  const int rh = wgid & 255;
  const int h = rh >> 1;
  const int halfx = (rh & 1) * 64;
  const int x_lo = halfx - 4;
  const int lane = threadIdx.x & 63, wave = threadIdx.x >> 6;
  const int l15 = lane & 15, l4 = lane >> 4;
  const int wx = halfx + wave * 16;
  const int p0 = h * WW + wx;
  const int myw = wx + l15;
  const int mypix = p0 + l15;
  const h16* xb = xt + (size_t)b * HWSZ * 64;
  const h16x8 zfr8 = {0, 0, 0, 0, 0, 0, 0, 0};

#pragma unroll
  for (int it = 0; it < 12; ++it) {
    int q = it * 256 + threadIdx.x;
    if (q < 2880) {
      int sp = q & 7, pr = q >> 3;
      int r = pr / 72, i = pr - r * 72;
      int gy = min(max(h - 2 + r, 0), HH - 1);
      int gx = min(max(x_lo + i, 0), WW - 1);
      int s = sp ^ (i & 7);
      const h16* src = xb + ((size_t)gy * WW + gx) * 64 + s * 8;
      __builtin_amdgcn_global_load_lds(
          (gptr_t)src, (lptr_t)(sh + (size_t)(it * 256 + wave * 64) * 8), 16, 0, 0);
    }
  }

  float offr[18];
  if constexpr (FUSED) {
    // stage t2 rows h-1..h+1, cols halfx-1..halfx+70 (72-wide), 32 ch
    const h16* t2b = aux + (size_t)b * HWSZ * 32;
#pragma unroll
    for (int it = 0; it < 4; ++it) {
      int q = it * 256 + threadIdx.x;
      if (q < 864) {
        int sp = q & 3, pr = q >> 2;
        int r = pr / 72, i = pr - r * 72;
        int gy = min(max(h - 1 + r, 0), HH - 1);
        int gx = min(max(halfx - 1 + i, 0), WW - 1);
        int s = sp ^ (i & 3);
        const h16* src = t2b + ((size_t)gy * WW + gx) * 32 + s * 8;
        __builtin_amdgcn_global_load_lds(
            (gptr_t)src, (lptr_t)(sh2 + (size_t)(it * 256 + wave * 64) * 8), 16, 0, 0);
      }
    }
    __syncthreads();
    // offset conv: D[o][px] over this wave's 16 pixels, K = 9*32
    f32x4 oa0 = (f32x4){0.f, 0.f, 0.f, 0.f};
    f32x4 oa1 = (f32x4){0.f, 0.f, 0.f, 0.f};
#pragma unroll
    for (int kt = 0; kt < 9; ++kt) {
      const int ki = kt / 3 - 1, kj = kt % 3 - 1;
      int y = h + ki;
      int xx = wx + l15 + kj;
      bool ok = ((unsigned)y < HH) && ((unsigned)xx < WW);
      int txc = min(max(xx, 0), WW - 1) - (halfx - 1);
      h16x8 av = ok ? *(const h16x8*)(sh2 + ((ki + 1) * 72 + txc) * 32 +
                                      ((l4 ^ (txc & 3)) * 8))
                    : zfr8;
      h16x8 w0 = *(const h16x8*)(fw2q + kt * 1024 + l15 * 32 + l4 * 8);
      h16x8 w1 = *(const h16x8*)(fw2q + kt * 1024 + 512 + l15 * 32 + l4 * 8);
      oa0 = __builtin_amdgcn_mfma_f32_16x16x32_f16(w0, av, oa0, 0, 0, 0);
      oa1 = __builtin_amdgcn_mfma_f32_16x16x32_f16(w1, av, oa1, 0, 0, 0);
    }
    __syncthreads();  // t2-tile reads complete; reuse sh2 as fp32 offsets
    float* shf2 = (float*)sh2;
#pragma unroll
    for (int r = 0; r < 4; ++r) {
      int o = l4 * 4 + r;
      shf2[(wave * 16 + l15) * 20 + o] = oa0[r] + fb2[o];
    }
    if (l4 == 0) {
      shf2[(wave * 16 + l15) * 20 + 16] = oa1[0] + fb2[16];
      shf2[(wave * 16 + l15) * 20 + 17] = oa1[1] + fb2[17];
    }
    __syncthreads();
#pragma unroll
    for (int e = 0; e < 18; ++e) offr[e] = shf2[(wave * 16 + l15) * 20 + e];
  } else {
    const h16* offp = aux + ((size_t)b * HWSZ + mypix) * 24;
    h16x8 offv0 = *(const h16x8*)(offp);
    h16x8 offv1 = *(const h16x8*)(offp + 8);
    h16x8 offv2 = *(const h16x8*)(offp + 16);
    __syncthreads();
#pragma unroll
    for (int e = 0; e < 18; ++e)
      offr[e] = (e < 8) ? (float)offv0[e & 7]
              : (e < 16) ? (float)offv1[e & 7] : (float)offv2[e & 7];
  }

  f32x4 acc[4];
#pragma unroll
  for (int og = 0; og < 4; ++og) acc[og] = (f32x4){0.f, 0.f, 0.f, 0.f};

  h16x8 pc[2][2][4];
  h16x8 pw[2][8];
  h16   pg[2][4];

#define PREF(kt, par) do {                                                  \
    float py = (float)(h + (kt) / 3 - 1) + offr[2 * (kt)];                  \
    float px = (float)(myw + (kt) % 3 - 1) + offr[2 * (kt) + 1];            \
    float y0f = floorf(py), x0f = floorf(px);                               \
    float wy1 = py - y0f, wy0 = 1.f - wy1;                                  \
    float wx1 = px - x0f, wx0 = 1.f - wx1;                                  \
    int y0 = (int)y0f, x0i = (int)x0f;                                      \
    int y1 = y0 + 1, x1i = x0i + 1;                                         \
    bool y0ok = (unsigned)y0 < HH, y1ok = (unsigned)y1 < HH;                \
    bool x0ok = (unsigned)x0i < WW, x1ok = (unsigned)x1i < WW;              \
    pg[par][0] = (h16)((y0ok && x0ok) ? wy0 * wx0 : 0.f);                   \
    pg[par][1] = (h16)((y0ok && x1ok) ? wy0 * wx1 : 0.f);                   \
    pg[par][2] = (h16)((y1ok && x0ok) ? wy1 * wx0 : 0.f);                   \
    pg[par][3] = (h16)((y1ok && x1ok) ? wy1 * wx1 : 0.f);                   \
    int y0c = min(max(y0, 0), HH - 1), y1c = min(max(y1, 0), HH - 1);       \
    int x0c = min(max(x0i, 0), WW - 1), x1c = min(max(x1i, 0), WW - 1);     \
    int ty0u = y0c - (h - 2), ty1u = y1c - (h - 2);                         \
    int tx0u = x0c - x_lo, tx1u = x1c - x_lo;                               \
    bool fast = ((unsigned)ty0u <= 4u) & ((unsigned)ty1u <= 4u) &           \
                ((unsigned)tx0u <= 71u) & ((unsigned)tx1u <= 71u);          \
    int ty0 = min(max(ty0u, 0), 4), ty1 = min(max(ty1u, 0), 4);             \
    int tx0 = min(max(tx0u, 0), 71), tx1 = min(max(tx1u, 0), 71);           \
    int pr00 = (ty0 * 72 + tx0) * 64, pr01 = (ty0 * 72 + tx1) * 64;         \
    int pr10 = (ty1 * 72 + tx0) * 64, pr11 = (ty1 * 72 + tx1) * 64;         \
    int sx0 = (tx0 & 7) * 8, sx1 = (tx1 & 7) * 8;                           \
    _Pragma("unroll")                                                       \
    for (int cg = 0; cg < 2; ++cg) {                                        \
      int sb = (cg * 4 + l4) * 8;                                           \
      pc[par][cg][0] = *(const h16x8*)(sh + pr00 + (sb ^ sx0));             \
      pc[par][cg][1] = *(const h16x8*)(sh + pr01 + (sb ^ sx1));             \
      pc[par][cg][2] = *(const h16x8*)(sh + pr10 + (sb ^ sx0));             \
      pc[par][cg][3] = *(const h16x8*)(sh + pr11 + (sb ^ sx1));             \
    }                                                                       \
    if (!fast) {                                                            \
      int i00 = y0c * WW + x0c, i01 = y0c * WW + x1c;                       \
      int i10 = y1c * WW + x0c, i11 = y1c * WW + x1c;                       \
      _Pragma("unroll")                                                     \
      for (int cg = 0; cg < 2; ++cg) {                                      \
        const h16* cb = xb + cg * 32 + l4 * 8;                              \
        pc[par][cg][0] = *(const h16x8*)(cb + (size_t)i00 * 64);            \
        pc[par][cg][1] = *(const h16x8*)(cb + (size_t)i01 * 64);            \
        pc[par][cg][2] = *(const h16x8*)(cb + (size_t)i10 * 64);            \
        pc[par][cg][3] = *(const h16x8*)(cb + (size_t)i11 * 64);            \
      }                                                                     \
    }                                                                       \
    const h16* wq0 = dwq + ((size_t)((kt) * 2 + 0) * 64 + l15) * 32 + l4 * 8; \
    const h16* wq1 = dwq + ((size_t)((kt) * 2 + 1) * 64 + l15) * 32 + l4 * 8; \
    pw[par][0] = *(const h16x8*)(wq0 + 0 * 512);                            \
    pw[par][1] = *(const h16x8*)(wq0 + 1 * 512);                            \
    pw[par][2] = *(const h16x8*)(wq0 + 2 * 512);                            \
    pw[par][3] = *(const h16x8*)(wq0 + 3 * 512);                            \
    pw[par][4] = *(const h16x8*)(wq1 + 0 * 512);                            \
    pw[par][5] = *(const h16x8*)(wq1 + 1 * 512);                            \
    pw[par][6] = *(const h16x8*)(wq1 + 2 * 512);                            \
    pw[par][7] = *(const h16x8*)(wq1 + 3 * 512);                            \
  } while (0)

#define CONS(par) do {                                                      \
    h16 w00 = pg[par][0], w01 = pg[par][1], w10 = pg[par][2], w11 = pg[par][3]; \
    h16x8 s0 = pc[par][0][0] * w00 + pc[par][0][1] * w01                    \
             + pc[par][0][2] * w10 + pc[par][0][3] * w11;                   \
    h16x8 s1 = pc[par][1][0] * w00 + pc[par][1][1] * w01                    \
             + pc[par][1][2] * w10 + pc[par][1][3] * w11;                   \
    acc[0] = __builtin_amdgcn_mfma_f32_16x16x32_f16(s0, pw[par][0], acc[0], 0, 0, 0); \
    acc[1] = __builtin_amdgcn_mfma_f32_16x16x32_f16(s0, pw[par][1], acc[1], 0, 0, 0); \
    acc[2] = __builtin_amdgcn_mfma_f32_16x16x32_f16(s0, pw[par][2], acc[2], 0, 0, 0); \
    acc[3] = __builtin_amdgcn_mfma_f32_16x16x32_f16(s0, pw[par][3], acc[3], 0, 0, 0); \
    acc[0] = __builtin_amdgcn_mfma_f32_16x16x32_f16(s1, pw[par][4], acc[0], 0, 0, 0); \
    acc[1] = __builtin_amdgcn_mfma_f32_16x16x32_f16(s1, pw[par][5], acc[1], 0, 0, 0); \
    acc[2] = __builtin_amdgcn_mfma_f32_16x16x32_f16(s1, pw[par][6], acc[2], 0, 0, 0); \
    acc[3] = __builtin_amdgcn_mfma_f32_16x16x32_f16(s1, pw[par][7], acc[3], 0, 0, 0); \
  } while (0)

  PREF(0, 0);
  PREF(1, 1);
  CONS(0);
  PREF(2, 0);
  CONS(1);
  PREF(3, 1);
  CONS(0);
  PREF(4, 0);
  CONS(1);
  PREF(5, 1);
  CONS(0);
  PREF(6, 0);
  CONS(1);
  PREF(7, 1);
  CONS(0);
  PREF(8, 0);
  CONS(1);
  CONS(0);
#undef PREF
#undef CONS

  float* outb = out + (size_t)b * CC * HWSZ;
#pragma unroll
  for (int og = 0; og < 4; ++og) {
    int o = og * 16 + l15;
    float bv = db[o];
    f32x4 st;
#pragma unroll
    for (int r = 0; r < 4; ++r) st[r] = fmaxf(acc[og][r] + bv, 0.f);
    *(f32x4*)(outb + (size_t)o * HWSZ + p0 + l4 * 4) = st;
  }
}

extern "C" void kernel_launch(void* const* d_in, const int* in_sizes, int n_in,
                              void* d_out, int out_size, void* d_ws, size_t ws_size,
                              hipStream_t stream) {
  const float* x     = (const float*)d_in[0];
  const float* bsize = (const float*)d_in[1];
  const float* gw1   = (const float*)d_in[2];
  const float* gb1   = (const float*)d_in[3];
  const float* gw2   = (const float*)d_in[4];
  const float* gb2   = (const float*)d_in[5];
  const float* lw1   = (const float*)d_in[6];
  const float* lb1   = (const float*)d_in[7];
  const float* lw2   = (const float*)d_in[8];
  const float* lb2   = (const float*)d_in[9];
  const float* fw1   = (const float*)d_in[10];
  const float* fb1   = (const float*)d_in[11];
  const float* fw2   = (const float*)d_in[12];
  const float* fb2   = (const float*)d_in[13];
  const float* dw    = (const float*)d_in[14];
  const float* db    = (const float*)d_in[15];
  float* out = (float*)d_out;

  const size_t XT  = (size_t)BB * HWSZ * 64 * 2;   // 16.78 MB
  const size_t T2  = (size_t)BB * HWSZ * 32 * 2;   // 8.39 MB
  const size_t OFC = (size_t)BB * HWSZ * 24 * 2;   // 6.29 MB
  const size_t DWQ = 36864 * 2;
  const size_t FW2 = 9216 * 2;
  const bool fused = ws_size >= 2048 + XT + T2 + DWQ + FW2;

  float* gbuf = (float*)d_ws;
  h16* xt = (h16*)((char*)d_ws + 2048);
  h16 *t2ws, *offc, *dwq, *fw2w;
  if (fused) {
    t2ws = (h16*)((char*)xt + XT);
    dwq  = (h16*)((char*)t2ws + T2);
    fw2w = (h16*)((char*)dwq + DWQ);
    offc = nullptr;
  } else {
    offc = (h16*)((char*)xt + XT);
    dwq  = (h16*)((char*)offc + OFC);
    fw2w = offc;  // scratch; overwritten later by conv4 (serial, safe)
    t2ws = nullptr;
  }

  // d_out scratch: loff f16 CL @0 | cwq @8.39MB | t1 (+t2 in fallback) @16.78MB
  h16* loff = (h16*)d_out;
  h16* cwq  = (h16*)d_out + 4194304;
  h16* t12  = (h16*)d_out + 8388608;
  const h16* lw1q = cwq;
  const h16* lw2q = cwq + 18432;
  const h16* fw1q = cwq + 27648;
  const h16* fw2q = cwq + 46080;

  prep_kernel<<<873, 256, 0, stream>>>(bsize, gw1, gb1, gw2, gb2, gbuf,
                                       lw1, lw2, fw1, fw2, dw, cwq, dwq, fw2w, x, xt);
  // t1 = relu(conv(x, lw1))
  conv_mfma_kernel<2, false, true, 0><<<512, 512, 0, stream>>>(
      xt, lw1q, lb1, nullptr, t12);
  // loff = conv(t1, lw2)
  conv_mfma_kernel<1, false, false, 0><<<512, 512, 0, stream>>>(
      t12, lw2q, lb2, nullptr, loff);
  if (fused) {
    // t2 = relu(conv(concat(g, loff), fw1)) -> ws (deform overwrites all of d_out)
    conv_mfma_kernel<2, true, true, 0><<<512, 512, 0, stream>>>(
        loff, fw1q, fb1, gbuf, t2ws);
    // deform with in-kernel offset conv
    deform_mfma_kernel<true><<<2048, 256, 0, stream>>>(
        xt, t2ws, dwq, db, fw2w, fb2, out);
  } else {
    conv_mfma_kernel<2, true, true, 0><<<512, 512, 0, stream>>>(
        loff, fw1q, fb1, gbuf, t12);
    conv_mfma_kernel<1, false, false, 1><<<512, 512, 0, stream>>>(
        t12, fw2q, fb2, nullptr, offc);
    deform_mfma_kernel<false><<<2048, 256, 0, stream>>>(
        xt, offc, dwq, db, nullptr, nullptr, out);
  }
}

// Round 19
// 102.210 us; speedup vs baseline: 1.0168x; 1.0168x over previous
//
#include <hip/hip_runtime.h>

#define BB 8
#define CC 64
#define HH 128
#define WW 128
#define HWSZ (HH*WW)

typedef _Float16 h16;
typedef __attribute__((ext_vector_type(8))) _Float16 h16x8;
typedef __attribute__((ext_vector_type(4))) _Float16 h16x4;
typedef __attribute__((ext_vector_type(2))) _Float16 h16x2;
typedef __attribute__((ext_vector_type(4))) float f32x4;

typedef const __attribute__((address_space(1))) unsigned int* gptr_t;
typedef __attribute__((address_space(3))) unsigned int* lptr_t;

// ---- pack helper ----
__device__ __forceinline__ void conv_pack(int j, int NCG, const float* w,
                                          int maxo, h16* dst) {
  int e = j & 7, l4 = (j >> 3) & 3, l15 = (j >> 5) & 15, f = (j >> 9) & 1;
  int cg = (j >> 10) & (NCG - 1), kt = (j >> 10) / NCG;
  int o = f * 16 + l15, c = cg * 32 + l4 * 8 + e;
  int CINw = NCG * 32;
  dst[j] = (o < maxo) ? (h16)w[(o * CINw + c) * 9 + kt] : (h16)0.f;
}

// ---------------- fused prep: g-MLP + weight pack + x transpose ----------------
__global__ __launch_bounds__(256) void prep_kernel(
    const float* __restrict__ bsize, const float* __restrict__ gw1,
    const float* __restrict__ gb1, const float* __restrict__ gw2,
    const float* __restrict__ gb2, float* __restrict__ g,
    const float* __restrict__ lw1, const float* __restrict__ lw2,
    const float* __restrict__ fw1, const float* __restrict__ fw2,
    const float* __restrict__ dw, h16* __restrict__ cwq,
    h16* __restrict__ dwq, const float* __restrict__ x,
    h16* __restrict__ xt) {
  __shared__ float hbuf[BB][64];
  const int blk = blockIdx.x;
  const int tid = threadIdx.x;
  if (blk == 0) {
#pragma unroll
    for (int i2 = 0; i2 < 2; ++i2) {
      int idx = i2 * 256 + tid;
      int b = idx >> 6, i = idx & 63;
      float v = fmaf(bsize[b * 2 + 0], gw1[i * 2 + 0],
                     fmaf(bsize[b * 2 + 1], gw1[i * 2 + 1], gb1[i]));
      hbuf[b][i] = fmaxf(v, 0.f);
    }
    __syncthreads();
    int b = tid >> 5, j = tid & 31;
    float acc = gb2[j];
#pragma unroll
    for (int i = 0; i < 64; ++i) acc = fmaf(hbuf[b][i], gw2[j * 64 + i], acc);
    g[b * 32 + j] = acc;
  } else if (blk <= 360) {
    int i = (blk - 1) * 256 + tid;
    if (i < 18432) {
      conv_pack(i, 2, lw1, 32, cwq);
    } else if (i < 27648) {
      conv_pack(i - 18432, 1, lw2, 32, cwq + 18432);
    } else if (i < 46080) {
      conv_pack(i - 27648, 2, fw1, 32, cwq + 27648);
    } else if (i < 55296) {
      conv_pack(i - 46080, 1, fw2, 18, cwq + 46080);
    } else if (i < 55296 + 36864) {
      int j = i - 55296;
      int e = j & 7, l4 = (j >> 3) & 3, l15 = (j >> 5) & 15;
      int og = (j >> 9) & 3, cg = (j >> 11) & 1, kt = j >> 12;
      int o = og * 16 + l15, c = cg * 32 + l4 * 8 + e;
      dwq[j] = (h16)dw[(o * 64 + c) * 9 + kt];
    }
  } else {
    int j = blk - 361;
    int b = (1 + j) & 7;
    int slot = j >> 3;
    int t = b * 16384 + slot * 256 + tid;
    int p = t & 16383;
    const float* xb = x + (size_t)b * 64 * HWSZ + p;
    h16* ob = xt + (size_t)t * 64;
#pragma unroll
    for (int c0 = 0; c0 < 64; c0 += 8) {
      h16x8 v;
#pragma unroll
      for (int i = 0; i < 8; ++i) v[i] = (h16)xb[(size_t)(c0 + i) * HWSZ];
      *(h16x8*)(ob + c0) = v;
    }
  }
}

// ---------------- conv 3x3 via MFMA + 4-row LDS tile, 2 output rows ----------------
// staging via async global_load_lds (linear LDS dest, pre-swizzled global src)
template <int NCG, bool GFUSE, bool RELU, int OMODE>
__global__ __launch_bounds__(512) void conv_mfma_kernel(
    const h16* __restrict__ in, const h16* __restrict__ cwq,
    const float* __restrict__ bias, const float* __restrict__ g,
    h16* __restrict__ outv) {
  constexpr int CINS = GFUSE ? 32 : NCG * 32;
  constexpr int NS = CINS / 8;
  constexpr int LOG2NS = (NS == 8) ? 3 : 2;
  constexpr int NCHUNK = 4 * 128 * NS;
  __shared__ __align__(16) h16 sh[4 * 128 * CINS];
  const int wgid = (blockIdx.x & 7) * 64 + (blockIdx.x >> 3);
  const int b = wgid >> 6;
  const int h0 = (wgid & 63) * 2;
  const int lane = threadIdx.x & 63, wave = threadIdx.x >> 6;
  const int wr = wave >> 2, wv = wave & 3;
  const int h = h0 + wr;
  const int l15 = lane & 15, l4 = lane >> 4;
  const h16* inb = in + (size_t)b * HWSZ * CINS;

  // stage rows h0-1..h0+2 async
#pragma unroll
  for (int it = 0; it < NCHUNK / 512; ++it) {
    int q = it * 512 + threadIdx.x;
    int sp = q & (NS - 1), pr = q >> LOG2NS;
    int r = pr >> 7, px = pr & 127;
    int gy = min(max(h0 - 1 + r, 0), HH - 1);
    int s = sp ^ (px & (NS - 1));
    const h16* src = inb + ((size_t)gy * WW + px) * CINS + s * 8;
    __builtin_amdgcn_global_load_lds(
        (gptr_t)src, (lptr_t)(sh + (size_t)(it * 512 + wave * 64) * 8), 16, 0, 0);
  }

  const h16x8 zfr = {0, 0, 0, 0, 0, 0, 0, 0};
  h16x8 gfr = zfr;
  if (GFUSE) {
#pragma unroll
    for (int i = 0; i < 8; ++i) gfr[i] = (h16)g[b * 32 + l4 * 8 + i];
  }
  __syncthreads();

  f32x4 acc[2][2];
#pragma unroll
  for (int f = 0; f < 2; ++f)
#pragma unroll
    for (int j = 0; j < 2; ++j) acc[f][j] = (f32x4){0.f, 0.f, 0.f, 0.f};

#pragma unroll
  for (int kt = 0; kt < 9; ++kt) {
    const int ki = kt / 3 - 1, kj = kt % 3 - 1;
    const int y = h + ki;
    const bool yok = (unsigned)y < HH;
    const int r = ki + 1 + wr;
    int xs[2];
    bool ok[2];
#pragma unroll
    for (int j = 0; j < 2; ++j) {
      int xx = wv * 32 + j * 16 + l15 + kj;
      ok[j] = yok && ((unsigned)xx < WW);
      xs[j] = min(max(xx, 0), WW - 1);
    }
#pragma unroll
    for (int cg = 0; cg < NCG; ++cg) {
      const h16* aq = cwq + (size_t)((kt * NCG + cg) * 2) * 512 + l15 * 32 + l4 * 8;
      h16x8 afr0 = *(const h16x8*)(aq);
      h16x8 afr1 = *(const h16x8*)(aq + 512);
#pragma unroll
      for (int j = 0; j < 2; ++j) {
        h16x8 bv;
        if (GFUSE && cg == 0) {
          bv = ok[j] ? gfr : zfr;
        } else {
          const int s = (!GFUSE && NCG == 2) ? cg * 4 + l4 : l4;
          h16x8 ld = *(const h16x8*)(sh + (r * 128 + xs[j]) * CINS +
                                     ((s ^ (xs[j] & (NS - 1))) * 8));
          bv = ok[j] ? ld : zfr;
        }
        acc[0][j] = __builtin_amdgcn_mfma_f32_16x16x32_f16(afr0, bv, acc[0][j], 0, 0, 0);
        acc[1][j] = __builtin_amdgcn_mfma_f32_16x16x32_f16(afr1, bv, acc[1][j], 0, 0, 0);
      }
    }
  }
  if (OMODE == 0) {
    h16* ob = outv + (size_t)b * HWSZ * 32;
#pragma unroll
    for (int f = 0; f < 2; ++f)
#pragma unroll
      for (int j = 0; j < 2; ++j) {
        int p = h * WW + wv * 32 + j * 16 + l15;
        int o0 = f * 16 + l4 * 4;
        h16x4 st;
#pragma unroll
        for (int r2 = 0; r2 < 4; ++r2) {
          float v = acc[f][j][r2] + bias[o0 + r2];
          if (RELU) v = fmaxf(v, 0.f);
          st[r2] = (h16)v;
        }
        *(h16x4*)(ob + (size_t)p * 32 + o0) = st;
      }
  } else {
    h16* ob = outv + (size_t)b * HWSZ * 24;
#pragma unroll
    for (int j = 0; j < 2; ++j) {
      int p = h * WW + wv * 32 + j * 16 + l15;
      {
        int o0 = l4 * 4;
        h16x4 st;
#pragma unroll
        for (int r2 = 0; r2 < 4; ++r2) st[r2] = (h16)(acc[0][j][r2] + bias[o0 + r2]);
        *(h16x4*)(ob + (size_t)p * 24 + o0) = st;
      }
      if (l4 == 0) {
        h16x2 st2;
        st2[0] = (h16)(acc[1][j][0] + bias[16]);
        st2[1] = (h16)(acc[1][j][1] + bias[17]);
        *(h16x2*)(ob + (size_t)p * 24 + 16) = st2;
      }
    }
  }
}

// ---------------- deformable conv: R8 geometry + async staging ----------------
__global__ __launch_bounds__(256) void deform_mfma_kernel(
    const h16* __restrict__ xt, const h16* __restrict__ offc,
    const h16* __restrict__ dwq, const float* __restrict__ db,
    float* __restrict__ out) {
  __shared__ __align__(16) h16 sh[5 * 72 * 64];
  const int wgid = (blockIdx.x & 7) * 256 + (blockIdx.x >> 3);
  const int b = wgid >> 8;
  const int rh = wgid & 255;
  const int h = rh >> 1;
  const int halfx = (rh & 1) * 64;
  const int x_lo = halfx - 4;
  const int lane = threadIdx.x & 63, wave = threadIdx.x >> 6;
  const int l15 = lane & 15, l4 = lane >> 4;
  const int wx = halfx + wave * 16;
  const int p0 = h * WW + wx;
  const int myw = wx + l15;
  const int mypix = p0 + l15;
  const h16* xb = xt + (size_t)b * HWSZ * 64;

  // ---- stage tile via async global_load_lds (linear dest, pre-swizzled src) ----
#pragma unroll
  for (int it = 0; it < 12; ++it) {
    int q = it * 256 + threadIdx.x;
    if (q < 2880) {
      int sp = q & 7, pr = q >> 3;
      int r = pr / 72, i = pr - r * 72;
      int gy = min(max(h - 2 + r, 0), HH - 1);
      int gx = min(max(x_lo + i, 0), WW - 1);
      int s = sp ^ (i & 7);
      const h16* src = xb + ((size_t)gy * WW + gx) * 64 + s * 8;
      __builtin_amdgcn_global_load_lds(
          (gptr_t)src, (lptr_t)(sh + (size_t)(it * 256 + wave * 64) * 8), 16, 0, 0);
    }
  }

  const h16* offp = offc + ((size_t)b * HWSZ + mypix) * 24;
  h16x8 offv0 = *(const h16x8*)(offp);
  h16x8 offv1 = *(const h16x8*)(offp + 8);
  h16x8 offv2 = *(const h16x8*)(offp + 16);
  __syncthreads();

#define OFFE(e) ((e) < 8 ? (float)offv0[(e) & 7] : (e) < 16 ? (float)offv1[(e) & 7] : (float)offv2[(e) & 7])

  f32x4 acc[4];
#pragma unroll
  for (int og = 0; og < 4; ++og) acc[og] = (f32x4){0.f, 0.f, 0.f, 0.f};

  h16x8 pc[2][2][4];
  h16x8 pw[2][8];
  h16   pg[2][4];

#define PREF(kt, par) do {                                                  \
    float py = (float)(h + (kt) / 3 - 1) + OFFE(2 * (kt));                  \
    float px = (float)(myw + (kt) % 3 - 1) + OFFE(2 * (kt) + 1);            \
    float y0f = floorf(py), x0f = floorf(px);                               \
    float wy1 = py - y0f, wy0 = 1.f - wy1;                                  \
    float wx1 = px - x0f, wx0 = 1.f - wx1;                                  \
    int y0 = (int)y0f, x0i = (int)x0f;                                      \
    int y1 = y0 + 1, x1i = x0i + 1;                                         \
    bool y0ok = (unsigned)y0 < HH, y1ok = (unsigned)y1 < HH;                \
    bool x0ok = (unsigned)x0i < WW, x1ok = (unsigned)x1i < WW;              \
    pg[par][0] = (h16)((y0ok && x0ok) ? wy0 * wx0 : 0.f);                   \
    pg[par][1] = (h16)((y0ok && x1ok) ? wy0 * wx1 : 0.f);                   \
    pg[par][2] = (h16)((y1ok && x0ok) ? wy1 * wx0 : 0.f);                   \
    pg[par][3] = (h16)((y1ok && x1ok) ? wy1 * wx1 : 0.f);                   \
    int y0c = min(max(y0, 0), HH - 1), y1c = min(max(y1, 0), HH - 1);       \
    int x0c = min(max(x0i, 0), WW - 1), x1c = min(max(x1i, 0), WW - 1);     \
    int ty0u = y0c - (h - 2), ty1u = y1c - (h - 2);                         \
    int tx0u = x0c - x_lo, tx1u = x1c - x_lo;                               \
    bool fast = ((unsigned)ty0u <= 4u) & ((unsigned)ty1u <= 4u) &           \
                ((unsigned)tx0u <= 71u) & ((unsigned)tx1u <= 71u);          \
    int ty0 = min(max(ty0u, 0), 4), ty1 = min(max(ty1u, 0), 4);             \
    int tx0 = min(max(tx0u, 0), 71), tx1 = min(max(tx1u, 0), 71);           \
    int pr00 = (ty0 * 72 + tx0) * 64, pr01 = (ty0 * 72 + tx1) * 64;         \
    int pr10 = (ty1 * 72 + tx0) * 64, pr11 = (ty1 * 72 + tx1) * 64;         \
    int sx0 = (tx0 & 7) * 8, sx1 = (tx1 & 7) * 8;                           \
    _Pragma("unroll")                                                       \
    for (int cg = 0; cg < 2; ++cg) {                                        \
      int sb = (cg * 4 + l4) * 8;                                           \
      pc[par][cg][0] = *(const h16x8*)(sh + pr00 + (sb ^ sx0));             \
      pc[par][cg][1] = *(const h16x8*)(sh + pr01 + (sb ^ sx1));             \
      pc[par][cg][2] = *(const h16x8*)(sh + pr10 + (sb ^ sx0));             \
      pc[par][cg][3] = *(const h16x8*)(sh + pr11 + (sb ^ sx1));             \
    }                                                                       \
    if (!fast) {                                                            \
      int i00 = y0c * WW + x0c, i01 = y0c * WW + x1c;                       \
      int i10 = y1c * WW + x0c, i11 = y1c * WW + x1c;                       \
      _Pragma("unroll")                                                     \
      for (int cg = 0; cg < 2; ++cg) {                                      \
        const h16* cb = xb + cg * 32 + l4 * 8;                              \
        pc[par][cg][0] = *(const h16x8*)(cb + (size_t)i00 * 64);            \
        pc[par][cg][1] = *(const h16x8*)(cb + (size_t)i01 * 64);            \
        pc[par][cg][2] = *(const h16x8*)(cb + (size_t)i10 * 64);            \
        pc[par][cg][3] = *(const h16x8*)(cb + (size_t)i11 * 64);            \
      }                                                                     \
    }                                                                       \
    const h16* wq0 = dwq + ((size_t)((kt) * 2 + 0) * 64 + l15) * 32 + l4 * 8; \
    const h16* wq1 = dwq + ((size_t)((kt) * 2 + 1) * 64 + l15) * 32 + l4 * 8; \
    pw[par][0] = *(const h16x8*)(wq0 + 0 * 512);                            \
    pw[par][1] = *(const h16x8*)(wq0 + 1 * 512);                            \
    pw[par][2] = *(const h16x8*)(wq0 + 2 * 512);                            \
    pw[par][3] = *(const h16x8*)(wq0 + 3 * 512);                            \
    pw[par][4] = *(const h16x8*)(wq1 + 0 * 512);                            \
    pw[par][5] = *(const h16x8*)(wq1 + 1 * 512);                            \
    pw[par][6] = *(const h16x8*)(wq1 + 2 * 512);                            \
    pw[par][7] = *(const h16x8*)(wq1 + 3 * 512);                            \
  } while (0)

#define CONS(par) do {                                                      \
    h16 w00 = pg[par][0], w01 = pg[par][1], w10 = pg[par][2], w11 = pg[par][3]; \
    h16x8 s0 = pc[par][0][0] * w00 + pc[par][0][1] * w01                    \
             + pc[par][0][2] * w10 + pc[par][0][3] * w11;                   \
    h16x8 s1 = pc[par][1][0] * w00 + pc[par][1][1] * w01                    \
             + pc[par][1][2] * w10 + pc[par][1][3] * w11;                   \
    acc[0] = __builtin_amdgcn_mfma_f32_16x16x32_f16(s0, pw[par][0], acc[0], 0, 0, 0); \
    acc[1] = __builtin_amdgcn_mfma_f32_16x16x32_f16(s0, pw[par][1], acc[1], 0, 0, 0); \
    acc[2] = __builtin_amdgcn_mfma_f32_16x16x32_f16(s0, pw[par][2], acc[2], 0, 0, 0); \
    acc[3] = __builtin_amdgcn_mfma_f32_16x16x32_f16(s0, pw[par][3], acc[3], 0, 0, 0); \
    acc[0] = __builtin_amdgcn_mfma_f32_16x16x32_f16(s1, pw[par][4], acc[0], 0, 0, 0); \
    acc[1] = __builtin_amdgcn_mfma_f32_16x16x32_f16(s1, pw[par][5], acc[1], 0, 0, 0); \
    acc[2] = __builtin_amdgcn_mfma_f32_16x16x32_f16(s1, pw[par][6], acc[2], 0, 0, 0); \
    acc[3] = __builtin_amdgcn_mfma_f32_16x16x32_f16(s1, pw[par][7], acc[3], 0, 0, 0); \
  } while (0)

  PREF(0, 0);
  PREF(1, 1);
  CONS(0);
  PREF(2, 0);
  CONS(1);
  PREF(3, 1);
  CONS(0);
  PREF(4, 0);
  CONS(1);
  PREF(5, 1);
  CONS(0);
  PREF(6, 0);
  CONS(1);
  PREF(7, 1);
  CONS(0);
  PREF(8, 0);
  CONS(1);
  CONS(0);
#undef PREF
#undef CONS
#undef OFFE

  float* outb = out + (size_t)b * CC * HWSZ;
#pragma unroll
  for (int og = 0; og < 4; ++og) {
    int o = og * 16 + l15;
    float bv = db[o];
    f32x4 st;
#pragma unroll
    for (int r = 0; r < 4; ++r) st[r] = fmaxf(acc[og][r] + bv, 0.f);
    *(f32x4*)(outb + (size_t)o * HWSZ + p0 + l4 * 4) = st;
  }
}

extern "C" void kernel_launch(void* const* d_in, const int* in_sizes, int n_in,
                              void* d_out, int out_size, void* d_ws, size_t ws_size,
                              hipStream_t stream) {
  const float* x     = (const float*)d_in[0];
  const float* bsize = (const float*)d_in[1];
  const float* gw1   = (const float*)d_in[2];
  const float* gb1   = (const float*)d_in[3];
  const float* gw2   = (const float*)d_in[4];
  const float* gb2   = (const float*)d_in[5];
  const float* lw1   = (const float*)d_in[6];
  const float* lb1   = (const float*)d_in[7];
  const float* lw2   = (const float*)d_in[8];
  const float* lb2   = (const float*)d_in[9];
  const float* fw1   = (const float*)d_in[10];
  const float* fb1   = (const float*)d_in[11];
  const float* fw2   = (const float*)d_in[12];
  const float* fb2   = (const float*)d_in[13];
  const float* dw    = (const float*)d_in[14];
  const float* db    = (const float*)d_in[15];
  float* out = (float*)d_out;

  // ws layout: gbuf(2KB) | xt f16 16.78MB | offc f16 [b][p][24] 6.29MB | dwq 72KB
  float* gbuf = (float*)d_ws;
  h16* xt   = (h16*)((char*)d_ws + 2048);
  h16* offc = (h16*)((char*)d_ws + 2048 + (size_t)BB * HWSZ * 64 * 2);
  h16* dwq  = (h16*)((char*)offc + (size_t)BB * HWSZ * 24 * 2);

  // d_out scratch: loff f16 CL @0 | cwq @8.39MB | t1/t2 f16 CL @16.78MB
  h16* loff = (h16*)d_out;
  h16* cwq  = (h16*)d_out + 4194304;
  h16* t12  = (h16*)d_out + 8388608;
  const h16* lw1q = cwq;
  const h16* lw2q = cwq + 18432;
  const h16* fw1q = cwq + 27648;
  const h16* fw2q = cwq + 46080;

  prep_kernel<<<873, 256, 0, stream>>>(bsize, gw1, gb1, gw2, gb2, gbuf,
                                       lw1, lw2, fw1, fw2, dw, cwq, dwq, x, xt);
  // t1 = relu(conv(x, lw1))
  conv_mfma_kernel<2, false, true, 0><<<512, 512, 0, stream>>>(
      xt, lw1q, lb1, nullptr, t12);
  // loff = conv(t1, lw2)
  conv_mfma_kernel<1, false, false, 0><<<512, 512, 0, stream>>>(
      t12, lw2q, lb2, nullptr, loff);
  // t2 = relu(conv(concat(g, loff), fw1))
  conv_mfma_kernel<2, true, true, 0><<<512, 512, 0, stream>>>(
      loff, fw1q, fb1, gbuf, t12);
  // offc = conv(t2, fw2), Cout=18, channel-last f16 stride 24
  conv_mfma_kernel<1, false, false, 1><<<512, 512, 0, stream>>>(
      t12, fw2q, fb2, nullptr, offc);
  // out = relu(deform_conv(x, offset, dw) + db)
  deform_mfma_kernel<<<2048, 256, 0, stream>>>(xt, offc, dwq, db, out);
}

// Round 20
// 101.599 us; speedup vs baseline: 1.0230x; 1.0060x over previous
//
#include <hip/hip_runtime.h>

#define BB 8
#define CC 64
#define HH 128
#define WW 128
#define HWSZ (HH*WW)

typedef _Float16 h16;
typedef __attribute__((ext_vector_type(8))) _Float16 h16x8;
typedef __attribute__((ext_vector_type(4))) _Float16 h16x4;
typedef __attribute__((ext_vector_type(2))) _Float16 h16x2;
typedef __attribute__((ext_vector_type(4))) float f32x4;

typedef const __attribute__((address_space(1))) unsigned int* gptr_t;
typedef __attribute__((address_space(3))) unsigned int* lptr_t;

// ---- pack helper ----
__device__ __forceinline__ void conv_pack(int j, int NCG, const float* w,
                                          int maxo, h16* dst) {
  int e = j & 7, l4 = (j >> 3) & 3, l15 = (j >> 5) & 15, f = (j >> 9) & 1;
  int cg = (j >> 10) & (NCG - 1), kt = (j >> 10) / NCG;
  int o = f * 16 + l15, c = cg * 32 + l4 * 8 + e;
  int CINw = NCG * 32;
  dst[j] = (o < maxo) ? (h16)w[(o * CINw + c) * 9 + kt] : (h16)0.f;
}

// ---------------- fused prep: g-MLP + weight pack + x transpose ----------------
__global__ __launch_bounds__(256) void prep_kernel(
    const float* __restrict__ bsize, const float* __restrict__ gw1,
    const float* __restrict__ gb1, const float* __restrict__ gw2,
    const float* __restrict__ gb2, float* __restrict__ g,
    const float* __restrict__ lw1, const float* __restrict__ lw2,
    const float* __restrict__ fw1, const float* __restrict__ fw2,
    const float* __restrict__ dw, h16* __restrict__ cwq,
    h16* __restrict__ dwq, const float* __restrict__ x,
    h16* __restrict__ xt) {
  __shared__ float hbuf[BB][64];
  const int blk = blockIdx.x;
  const int tid = threadIdx.x;
  if (blk == 0) {
#pragma unroll
    for (int i2 = 0; i2 < 2; ++i2) {
      int idx = i2 * 256 + tid;
      int b = idx >> 6, i = idx & 63;
      float v = fmaf(bsize[b * 2 + 0], gw1[i * 2 + 0],
                     fmaf(bsize[b * 2 + 1], gw1[i * 2 + 1], gb1[i]));
      hbuf[b][i] = fmaxf(v, 0.f);
    }
    __syncthreads();
    int b = tid >> 5, j = tid & 31;
    float acc = gb2[j];
#pragma unroll
    for (int i = 0; i < 64; ++i) acc = fmaf(hbuf[b][i], gw2[j * 64 + i], acc);
    g[b * 32 + j] = acc;
  } else if (blk <= 360) {
    int i = (blk - 1) * 256 + tid;
    if (i < 18432) {
      conv_pack(i, 2, lw1, 32, cwq);
    } else if (i < 27648) {
      conv_pack(i - 18432, 1, lw2, 32, cwq + 18432);
    } else if (i < 46080) {
      conv_pack(i - 27648, 2, fw1, 32, cwq + 27648);
    } else if (i < 55296) {
      conv_pack(i - 46080, 1, fw2, 18, cwq + 46080);
    } else if (i < 55296 + 36864) {
      int j = i - 55296;
      int e = j & 7, l4 = (j >> 3) & 3, l15 = (j >> 5) & 15;
      int og = (j >> 9) & 3, cg = (j >> 11) & 1, kt = j >> 12;
      int o = og * 16 + l15, c = cg * 32 + l4 * 8 + e;
      dwq[j] = (h16)dw[(o * 64 + c) * 9 + kt];
    }
  } else {
    int j = blk - 361;
    int b = (1 + j) & 7;
    int slot = j >> 3;
    int t = b * 16384 + slot * 256 + tid;
    int p = t & 16383;
    const float* xb = x + (size_t)b * 64 * HWSZ + p;
    h16* ob = xt + (size_t)t * 64;
#pragma unroll
    for (int c0 = 0; c0 < 64; c0 += 8) {
      h16x8 v;
#pragma unroll
      for (int i = 0; i < 8; ++i) v[i] = (h16)xb[(size_t)(c0 + i) * HWSZ];
      *(h16x8*)(ob + c0) = v;
    }
  }
}

// ---------------- conv 3x3 via MFMA + 4-row LDS tile, 2 output rows (R12) ----------------
template <int NCG, bool GFUSE, bool RELU, int OMODE>
__global__ __launch_bounds__(512) void conv_mfma_kernel(
    const h16* __restrict__ in, const h16* __restrict__ cwq,
    const float* __restrict__ bias, const float* __restrict__ g,
    h16* __restrict__ outv) {
  constexpr int CINS = GFUSE ? 32 : NCG * 32;
  constexpr int NS = CINS / 8;
  constexpr int LOG2NS = (NS == 8) ? 3 : 2;
  constexpr int NCHUNK = 4 * 128 * NS;
  __shared__ __align__(16) h16 sh[4 * 128 * CINS];
  const int wgid = (blockIdx.x & 7) * 64 + (blockIdx.x >> 3);
  const int b = wgid >> 6;
  const int h0 = (wgid & 63) * 2;
  const int lane = threadIdx.x & 63, wave = threadIdx.x >> 6;
  const int wr = wave >> 2, wv = wave & 3;
  const int h = h0 + wr;
  const int l15 = lane & 15, l4 = lane >> 4;
  const h16* inb = in + (size_t)b * HWSZ * CINS;

#pragma unroll
  for (int it = 0; it < NCHUNK / 512; ++it) {
    int q = it * 512 + threadIdx.x;
    int sp = q & (NS - 1), pr = q >> LOG2NS;
    int r = pr >> 7, px = pr & 127;
    int gy = min(max(h0 - 1 + r, 0), HH - 1);
    int s = sp ^ (px & (NS - 1));
    const h16* src = inb + ((size_t)gy * WW + px) * CINS + s * 8;
    __builtin_amdgcn_global_load_lds(
        (gptr_t)src, (lptr_t)(sh + (size_t)(it * 512 + wave * 64) * 8), 16, 0, 0);
  }

  const h16x8 zfr = {0, 0, 0, 0, 0, 0, 0, 0};
  h16x8 gfr = zfr;
  if (GFUSE) {
#pragma unroll
    for (int i = 0; i < 8; ++i) gfr[i] = (h16)g[b * 32 + l4 * 8 + i];
  }
  __syncthreads();

  f32x4 acc[2][2];
#pragma unroll
  for (int f = 0; f < 2; ++f)
#pragma unroll
    for (int j = 0; j < 2; ++j) acc[f][j] = (f32x4){0.f, 0.f, 0.f, 0.f};

#pragma unroll
  for (int kt = 0; kt < 9; ++kt) {
    const int ki = kt / 3 - 1, kj = kt % 3 - 1;
    const int y = h + ki;
    const bool yok = (unsigned)y < HH;
    const int r = ki + 1 + wr;
    int xs[2];
    bool ok[2];
#pragma unroll
    for (int j = 0; j < 2; ++j) {
      int xx = wv * 32 + j * 16 + l15 + kj;
      ok[j] = yok && ((unsigned)xx < WW);
      xs[j] = min(max(xx, 0), WW - 1);
    }
#pragma unroll
    for (int cg = 0; cg < NCG; ++cg) {
      const h16* aq = cwq + (size_t)((kt * NCG + cg) * 2) * 512 + l15 * 32 + l4 * 8;
      h16x8 afr0 = *(const h16x8*)(aq);
      h16x8 afr1 = *(const h16x8*)(aq + 512);
#pragma unroll
      for (int j = 0; j < 2; ++j) {
        h16x8 bv;
        if (GFUSE && cg == 0) {
          bv = ok[j] ? gfr : zfr;
        } else {
          const int s = (!GFUSE && NCG == 2) ? cg * 4 + l4 : l4;
          h16x8 ld = *(const h16x8*)(sh + (r * 128 + xs[j]) * CINS +
                                     ((s ^ (xs[j] & (NS - 1))) * 8));
          bv = ok[j] ? ld : zfr;
        }
        acc[0][j] = __builtin_amdgcn_mfma_f32_16x16x32_f16(afr0, bv, acc[0][j], 0, 0, 0);
        acc[1][j] = __builtin_amdgcn_mfma_f32_16x16x32_f16(afr1, bv, acc[1][j], 0, 0, 0);
      }
    }
  }
  if (OMODE == 0) {
    h16* ob = outv + (size_t)b * HWSZ * 32;
#pragma unroll
    for (int f = 0; f < 2; ++f)
#pragma unroll
      for (int j = 0; j < 2; ++j) {
        int p = h * WW + wv * 32 + j * 16 + l15;
        int o0 = f * 16 + l4 * 4;
        h16x4 st;
#pragma unroll
        for (int r2 = 0; r2 < 4; ++r2) {
          float v = acc[f][j][r2] + bias[o0 + r2];
          if (RELU) v = fmaxf(v, 0.f);
          st[r2] = (h16)v;
        }
        *(h16x4*)(ob + (size_t)p * 32 + o0) = st;
      }
  } else {
    h16* ob = outv + (size_t)b * HWSZ * 24;
#pragma unroll
    for (int j = 0; j < 2; ++j) {
      int p = h * WW + wv * 32 + j * 16 + l15;
      {
        int o0 = l4 * 4;
        h16x4 st;
#pragma unroll
        for (int r2 = 0; r2 < 4; ++r2) st[r2] = (h16)(acc[0][j][r2] + bias[o0 + r2]);
        *(h16x4*)(ob + (size_t)p * 24 + o0) = st;
      }
      if (l4 == 0) {
        h16x2 st2;
        st2[0] = (h16)(acc[1][j][0] + bias[16]);
        st2[1] = (h16)(acc[1][j][1] + bias[17]);
        *(h16x2*)(ob + (size_t)p * 24 + 16) = st2;
      }
    }
  }
}

// ---------------- deformable conv: quarter-row blocks, 5x40 tile (25.6KB) ----------------
// block = 128 thr = 2 waves x 16 px. grid = 4096.
__global__ __launch_bounds__(128) void deform_mfma_kernel(
    const h16* __restrict__ xt, const h16* __restrict__ offc,
    const h16* __restrict__ dwq, const float* __restrict__ db,
    float* __restrict__ out) {
  __shared__ __align__(16) h16 sh[5 * 40 * 64];
  const int wgid = (blockIdx.x & 7) * 512 + (blockIdx.x >> 3);
  const int b = wgid >> 9;
  const int rh = wgid & 511;
  const int h = rh >> 2;
  const int qx = (rh & 3) * 32;
  const int x_lo = qx - 4;
  const int lane = threadIdx.x & 63, wave = threadIdx.x >> 6;
  const int l15 = lane & 15, l4 = lane >> 4;
  const int wx = qx + wave * 16;
  const int p0 = h * WW + wx;
  const int myw = wx + l15;
  const int mypix = p0 + l15;
  const h16* xb = xt + (size_t)b * HWSZ * 64;

  // ---- stage 5x40x64 tile async (linear dest, pre-swizzled src) ----
#pragma unroll
  for (int it = 0; it < 13; ++it) {
    int q = it * 128 + threadIdx.x;
    if (q < 1600) {
      int sp = q & 7, pr = q >> 3;
      int r = pr / 40, i = pr - r * 40;
      int gy = min(max(h - 2 + r, 0), HH - 1);
      int gx = min(max(x_lo + i, 0), WW - 1);
      int s = sp ^ (i & 7);
      const h16* src = xb + ((size_t)gy * WW + gx) * 64 + s * 8;
      __builtin_amdgcn_global_load_lds(
          (gptr_t)src, (lptr_t)(sh + (size_t)(it * 128 + wave * 64) * 8), 16, 0, 0);
    }
  }

  const h16* offp = offc + ((size_t)b * HWSZ + mypix) * 24;
  h16x8 offv0 = *(const h16x8*)(offp);
  h16x8 offv1 = *(const h16x8*)(offp + 8);
  h16x8 offv2 = *(const h16x8*)(offp + 16);
  __syncthreads();

#define OFFE(e) ((e) < 8 ? (float)offv0[(e) & 7] : (e) < 16 ? (float)offv1[(e) & 7] : (float)offv2[(e) & 7])

  f32x4 acc[4];
#pragma unroll
  for (int og = 0; og < 4; ++og) acc[og] = (f32x4){0.f, 0.f, 0.f, 0.f};

  h16x8 pc[2][2][4];
  h16x8 pw[2][8];
  h16   pg[2][4];

#define PREF(kt, par) do {                                                  \
    float py = (float)(h + (kt) / 3 - 1) + OFFE(2 * (kt));                  \
    float px = (float)(myw + (kt) % 3 - 1) + OFFE(2 * (kt) + 1);            \
    float y0f = floorf(py), x0f = floorf(px);                               \
    float wy1 = py - y0f, wy0 = 1.f - wy1;                                  \
    float wx1 = px - x0f, wx0 = 1.f - wx1;                                  \
    int y0 = (int)y0f, x0i = (int)x0f;                                      \
    int y1 = y0 + 1, x1i = x0i + 1;                                         \
    bool y0ok = (unsigned)y0 < HH, y1ok = (unsigned)y1 < HH;                \
    bool x0ok = (unsigned)x0i < WW, x1ok = (unsigned)x1i < WW;              \
    pg[par][0] = (h16)((y0ok && x0ok) ? wy0 * wx0 : 0.f);                   \
    pg[par][1] = (h16)((y0ok && x1ok) ? wy0 * wx1 : 0.f);                   \
    pg[par][2] = (h16)((y1ok && x0ok) ? wy1 * wx0 : 0.f);                   \
    pg[par][3] = (h16)((y1ok && x1ok) ? wy1 * wx1 : 0.f);                   \
    int y0c = min(max(y0, 0), HH - 1), y1c = min(max(y1, 0), HH - 1);       \
    int x0c = min(max(x0i, 0), WW - 1), x1c = min(max(x1i, 0), WW - 1);     \
    int ty0u = y0c - (h - 2), ty1u = y1c - (h - 2);                         \
    int tx0u = x0c - x_lo, tx1u = x1c - x_lo;                               \
    bool fast = ((unsigned)ty0u <= 4u) & ((unsigned)ty1u <= 4u) &           \
                ((unsigned)tx0u <= 39u) & ((unsigned)tx1u <= 39u);          \
    int ty0 = min(max(ty0u, 0), 4), ty1 = min(max(ty1u, 0), 4);             \
    int tx0 = min(max(tx0u, 0), 39), tx1 = min(max(tx1u, 0), 39);           \
    int pr00 = (ty0 * 40 + tx0) * 64, pr01 = (ty0 * 40 + tx1) * 64;         \
    int pr10 = (ty1 * 40 + tx0) * 64, pr11 = (ty1 * 40 + tx1) * 64;         \
    int sx0 = (tx0 & 7) * 8, sx1 = (tx1 & 7) * 8;                           \
    _Pragma("unroll")                                                       \
    for (int cg = 0; cg < 2; ++cg) {                                        \
      int sb = (cg * 4 + l4) * 8;                                           \
      pc[par][cg][0] = *(const h16x8*)(sh + pr00 + (sb ^ sx0));             \
      pc[par][cg][1] = *(const h16x8*)(sh + pr01 + (sb ^ sx1));             \
      pc[par][cg][2] = *(const h16x8*)(sh + pr10 + (sb ^ sx0));             \
      pc[par][cg][3] = *(const h16x8*)(sh + pr11 + (sb ^ sx1));             \
    }                                                                       \
    if (!fast) {                                                            \
      int i00 = y0c * WW + x0c, i01 = y0c * WW + x1c;                       \
      int i10 = y1c * WW + x0c, i11 = y1c * WW + x1c;                       \
      _Pragma("unroll")                                                     \
      for (int cg = 0; cg < 2; ++cg) {                                      \
        const h16* cb = xb + cg * 32 + l4 * 8;                              \
        pc[par][cg][0] = *(const h16x8*)(cb + (size_t)i00 * 64);            \
        pc[par][cg][1] = *(const h16x8*)(cb + (size_t)i01 * 64);            \
        pc[par][cg][2] = *(const h16x8*)(cb + (size_t)i10 * 64);            \
        pc[par][cg][3] = *(const h16x8*)(cb + (size_t)i11 * 64);            \
      }                                                                     \
    }                                                                       \
    const h16* wq0 = dwq + ((size_t)((kt) * 2 + 0) * 64 + l15) * 32 + l4 * 8; \
    const h16* wq1 = dwq + ((size_t)((kt) * 2 + 1) * 64 + l15) * 32 + l4 * 8; \
    pw[par][0] = *(const h16x8*)(wq0 + 0 * 512);                            \
    pw[par][1] = *(const h16x8*)(wq0 + 1 * 512);                            \
    pw[par][2] = *(const h16x8*)(wq0 + 2 * 512);                            \
    pw[par][3] = *(const h16x8*)(wq0 + 3 * 512);                            \
    pw[par][4] = *(const h16x8*)(wq1 + 0 * 512);                            \
    pw[par][5] = *(const h16x8*)(wq1 + 1 * 512);                            \
    pw[par][6] = *(const h16x8*)(wq1 + 2 * 512);                            \
    pw[par][7] = *(const h16x8*)(wq1 + 3 * 512);                            \
  } while (0)

#define CONS(par) do {                                                      \
    h16 w00 = pg[par][0], w01 = pg[par][1], w10 = pg[par][2], w11 = pg[par][3]; \
    h16x8 s0 = pc[par][0][0] * w00 + pc[par][0][1] * w01                    \
             + pc[par][0][2] * w10 + pc[par][0][3] * w11;                   \
    h16x8 s1 = pc[par][1][0] * w00 + pc[par][1][1] * w01                    \
             + pc[par][1][2] * w10 + pc[par][1][3] * w11;                   \
    acc[0] = __builtin_amdgcn_mfma_f32_16x16x32_f16(s0, pw[par][0], acc[0], 0, 0, 0); \
    acc[1] = __builtin_amdgcn_mfma_f32_16x16x32_f16(s0, pw[par][1], acc[1], 0, 0, 0); \
    acc[2] = __builtin_amdgcn_mfma_f32_16x16x32_f16(s0, pw[par][2], acc[2], 0, 0, 0); \
    acc[3] = __builtin_amdgcn_mfma_f32_16x16x32_f16(s0, pw[par][3], acc[3], 0, 0, 0); \
    acc[0] = __builtin_amdgcn_mfma_f32_16x16x32_f16(s1, pw[par][4], acc[0], 0, 0, 0); \
    acc[1] = __builtin_amdgcn_mfma_f32_16x16x32_f16(s1, pw[par][5], acc[1], 0, 0, 0); \
    acc[2] = __builtin_amdgcn_mfma_f32_16x16x32_f16(s1, pw[par][6], acc[2], 0, 0, 0); \
    acc[3] = __builtin_amdgcn_mfma_f32_16x16x32_f16(s1, pw[par][7], acc[3], 0, 0, 0); \
  } while (0)

  PREF(0, 0);
  PREF(1, 1);
  CONS(0);
  PREF(2, 0);
  CONS(1);
  PREF(3, 1);
  CONS(0);
  PREF(4, 0);
  CONS(1);
  PREF(5, 1);
  CONS(0);
  PREF(6, 0);
  CONS(1);
  PREF(7, 1);
  CONS(0);
  PREF(8, 0);
  CONS(1);
  CONS(0);
#undef PREF
#undef CONS
#undef OFFE

  float* outb = out + (size_t)b * CC * HWSZ;
#pragma unroll
  for (int og = 0; og < 4; ++og) {
    int o = og * 16 + l15;
    float bv = db[o];
    f32x4 st;
#pragma unroll
    for (int r = 0; r < 4; ++r) st[r] = fmaxf(acc[og][r] + bv, 0.f);
    *(f32x4*)(outb + (size_t)o * HWSZ + p0 + l4 * 4) = st;
  }
}

extern "C" void kernel_launch(void* const* d_in, const int* in_sizes, int n_in,
                              void* d_out, int out_size, void* d_ws, size_t ws_size,
                              hipStream_t stream) {
  const float* x     = (const float*)d_in[0];
  const float* bsize = (const float*)d_in[1];
  const float* gw1   = (const float*)d_in[2];
  const float* gb1   = (const float*)d_in[3];
  const float* gw2   = (const float*)d_in[4];
  const float* gb2   = (const float*)d_in[5];
  const float* lw1   = (const float*)d_in[6];
  const float* lb1   = (const float*)d_in[7];
  const float* lw2   = (const float*)d_in[8];
  const float* lb2   = (const float*)d_in[9];
  const float* fw1   = (const float*)d_in[10];
  const float* fb1   = (const float*)d_in[11];
  const float* fw2   = (const float*)d_in[12];
  const float* fb2   = (const float*)d_in[13];
  const float* dw    = (const float*)d_in[14];
  const float* db    = (const float*)d_in[15];
  float* out = (float*)d_out;

  // ws layout: gbuf(2KB) | xt f16 16.78MB | offc f16 [b][p][24] 6.29MB | dwq 72KB
  float* gbuf = (float*)d_ws;
  h16* xt   = (h16*)((char*)d_ws + 2048);
  h16* offc = (h16*)((char*)d_ws + 2048 + (size_t)BB * HWSZ * 64 * 2);
  h16* dwq  = (h16*)((char*)offc + (size_t)BB * HWSZ * 24 * 2);

  // d_out scratch: loff f16 CL @0 | cwq @8.39MB | t1/t2 f16 CL @16.78MB
  h16* loff = (h16*)d_out;
  h16* cwq  = (h16*)d_out + 4194304;
  h16* t12  = (h16*)d_out + 8388608;
  const h16* lw1q = cwq;
  const h16* lw2q = cwq + 18432;
  const h16* fw1q = cwq + 27648;
  const h16* fw2q = cwq + 46080;

  prep_kernel<<<873, 256, 0, stream>>>(bsize, gw1, gb1, gw2, gb2, gbuf,
                                       lw1, lw2, fw1, fw2, dw, cwq, dwq, x, xt);
  // t1 = relu(conv(x, lw1))
  conv_mfma_kernel<2, false, true, 0><<<512, 512, 0, stream>>>(
      xt, lw1q, lb1, nullptr, t12);
  // loff = conv(t1, lw2)
  conv_mfma_kernel<1, false, false, 0><<<512, 512, 0, stream>>>(
      t12, lw2q, lb2, nullptr, loff);
  // t2 = relu(conv(concat(g, loff), fw1))
  conv_mfma_kernel<2, true, true, 0><<<512, 512, 0, stream>>>(
      loff, fw1q, fb1, gbuf, t12);
  // offc = conv(t2, fw2), Cout=18, channel-last f16 stride 24
  conv_mfma_kernel<1, false, false, 1><<<512, 512, 0, stream>>>(
      t12, fw2q, fb2, nullptr, offc);
  // out = relu(deform_conv(x, offset, dw) + db)
  deform_mfma_kernel<<<4096, 128, 0, stream>>>(xt, offc, dwq, db, out);
}